// Round 13
// baseline (186.861 us; speedup 1.0000x reference)
//
#include <hip/hip_runtime.h>
#include <math.h>

// RelationalKENN R19: R18 + 4-way lane-replicated LDS accumulators in tile_acc.
//
// Ledger:
//  R10 global packed-u64 atomics: REFUTED (~32B HBM write each, 287us).
//  R11/R16 NB=1024: REFUTED TWICE — bin is L2-capacity-bound. NB=512 final.
//  R12 cooperative fusion: REFUTED (252us).
//  R13b nt-everything: nt loads fix u_lo thrash; nt entries store breaks
//      write-combining (reverted).
//  R14 nt loads + nt out_b: WIN (190.3).
//  R15 pass-2 atomic removal: NEUTRAL — exonerated.
//  R17 TILE_N=200: WASH — bin/acc coupled via T; T=250 best.
//  R18 12B entries + 1024-thr acc: WIN (185.4). BEST.
//  R19 theory: acc ~50+us is LDS ds_add_u64 same-address serialization:
//      64 lanes -> 400 slots => multiplicity 3-4 per issue + >=4-way bank
//      aliasing. Fix: replica rep=tid&3, pitch 404 (banks staggered by 8);
//      within-wave same-id collisions /4. Fold sums 4 packed replicas
//      (mixed-radix packing is additive => bit-identical numerics).
//      Predict: bin ~88 flat; total ->172-178 if collision-bound;
//      flat => acc exonerated, remainder is gaps => near-structural.

#define NU 16
#define NC 8
#define TILE_N 400u
#define NB 512        // bin-pass blocks
#define BT 512        // bin-pass block size
#define CACHE_N 3200  // max edges cached per bin block (chunk = 3125)
#define ACC_ST 400
#define ACC_PITCH 404 // 404*8B = 808 words == 8 mod 32 -> replica bank stagger
#define BTA 1024      // tile_acc block size

typedef float    f32x4 __attribute__((ext_vector_type(4)));
typedef unsigned u32x4 __attribute__((ext_vector_type(4)));

__device__ __forceinline__ int q10(float x) {
    int q = __float2int_rn(x * 512.0f);
    q = q < -511 ? -511 : (q > 511 ? 511 : q);
    return q & 0x3FF;
}
__device__ __forceinline__ int sx10(unsigned w, int sh) {
    return ((int)(w << (22 - sh))) >> 22;
}
__device__ __forceinline__ unsigned long long pk4(int a0, int a1, int a2, int a3) {
    return (unsigned long long)(long long)a0 +
           ((unsigned long long)(long long)a1 << 16) +
           ((unsigned long long)(long long)a2 << 32) +
           ((unsigned long long)(unsigned short)a3 << 48);
}

__global__ void unary_enhance_kernel(const float* __restrict__ unary,
                                     const float* __restrict__ ucw,
                                     float* __restrict__ out_u,   // [n_nodes*16]
                                     float* __restrict__ u_lo,    // [n_nodes*8]
                                     unsigned* __restrict__ cursor, // [T] or null
                                     int n_nodes, int T) {
    int n = blockIdx.x * blockDim.x + threadIdx.x;
    if (cursor && n < T) cursor[n] = 0u;
    if (n >= n_nodes) return;

    float x[NU];
    const float4* src = (const float4*)(unary + (size_t)n * NU);
#pragma unroll
    for (int j = 0; j < 4; ++j) {
        float4 v = src[j];
        x[4*j+0] = v.x; x[4*j+1] = v.y; x[4*j+2] = v.z; x[4*j+3] = v.w;
    }
    float dlt[NU];
#pragma unroll
    for (int j = 0; j < NU; ++j) dlt[j] = 0.0f;
#pragma unroll
    for (int i = 0; i < NC; ++i) {
        float w = ucw[i];
        float a = -x[i], b = x[i+1], c = x[i+2];
        float m = fmaxf(a, fmaxf(b, c));
        float e0 = __expf(a - m);
        float e1 = __expf(b - m);
        float e2 = __expf(c - m);
        float inv = 1.0f / (e0 + e1 + e2);
        dlt[i]   -= w * e0 * inv;
        dlt[i+1] += w * e1 * inv;
        dlt[i+2] += w * e2 * inv;
    }
    float u[NU];
#pragma unroll
    for (int j = 0; j < NU; ++j) u[j] = x[j] + dlt[j];

    float4* dst = (float4*)(out_u + (size_t)n * NU);
#pragma unroll
    for (int j = 0; j < 4; ++j) {
        float4 v; v.x = u[4*j+0]; v.y = u[4*j+1]; v.z = u[4*j+2]; v.w = u[4*j+3];
        dst[j] = v;
    }
    // u_lo: NORMAL store — we WANT it resident in L2 for bin's gathers.
    float4* lo = (float4*)(u_lo + (size_t)n * 8);
    float4 l0; l0.x = u[0]; l0.y = u[1]; l0.z = u[2]; l0.w = u[3];
    float4 l1; l1.x = u[4]; l1.y = u[5]; l1.z = u[6]; l1.w = u[7];
    lo[0] = l0; lo[1] = l1;
}

// Softmax + out_b + 2 scatter entries (12B each) for one edge.
__device__ __forceinline__ void edge_body(int e, int i1, int i2, f32x4 bv,
                                          float4 a0, float4 a1, float4 c0, float4 c1,
                                          const float* w,
                                          float* __restrict__ out_b,
                                          unsigned* hist,
                                          unsigned* __restrict__ entries,
                                          float* __restrict__ out_u,
                                          int cap) {
    float b[4] = {bv.x, bv.y, bv.z, bv.w};
    float u1[8] = {a0.x,a0.y,a0.z,a0.w,a1.x,a1.y,a1.z,a1.w};
    float u2[8] = {c0.x,c0.y,c0.z,c0.w,c1.x,c1.y,c1.z,c1.w};

    float d1[8], d2[8], dbp[4] = {0.f,0.f,0.f,0.f};
#pragma unroll
    for (int i = 0; i < NC; ++i) {
        float a = -u1[i], bb = b[i & 3], c = u2[i];
        float m = fmaxf(a, fmaxf(bb, c));
        float e0x = __expf(a - m);
        float e1x = __expf(bb - m);
        float e2x = __expf(c - m);
        float inv = 1.0f / (e0x + e1x + e2x);
        d1[i] = -w[i] * e0x * inv;
        d2[i] =  w[i] * e2x * inv;
        dbp[i & 3] += w[i] * e1x * inv;
    }
    f32x4 ob;
    ob.x = b[0] + dbp[0];
    ob.y = b[1] + dbp[1];
    ob.z = b[2] + dbp[2];
    ob.w = b[3] + dbp[3];
    // coalesced 1KB/wave stream: nt write-combines fine, no L2 pollution
    __builtin_nontemporal_store(ob, ((f32x4*)out_b) + e);

    unsigned t1 = (unsigned)i1 / TILE_N;
    unsigned id1 = (unsigned)i1 - t1 * TILE_N;
    unsigned slot1 = atomicAdd(&hist[t1], 1u);
    if (slot1 < (unsigned)cap) {
        unsigned* ep = entries + ((size_t)t1 * cap + slot1) * 3;
        ep[0] = (unsigned)q10(d1[0]) | ((unsigned)q10(d1[1]) << 10) | ((unsigned)q10(d1[2]) << 20);
        ep[1] = (unsigned)q10(d1[3]) | ((unsigned)q10(d1[4]) << 10) | ((unsigned)q10(d1[5]) << 20);
        ep[2] = (unsigned)q10(d1[6]) | ((unsigned)q10(d1[7]) << 10) | (id1 << 20);
    } else {
        float* r = out_u + (size_t)i1 * NU;
#pragma unroll
        for (int i = 0; i < NC; ++i) atomicAdd(r + i, d1[i]);
    }

    unsigned t2 = (unsigned)i2 / TILE_N;
    unsigned id2 = (unsigned)i2 - t2 * TILE_N;
    unsigned slot2 = atomicAdd(&hist[t2], 1u);
    if (slot2 < (unsigned)cap) {
        unsigned* ep = entries + ((size_t)t2 * cap + slot2) * 3;
        ep[0] = (unsigned)q10(d2[0]) | ((unsigned)q10(d2[1]) << 10) | ((unsigned)q10(d2[2]) << 20);
        ep[1] = (unsigned)q10(d2[3]) | ((unsigned)q10(d2[4]) << 10) | ((unsigned)q10(d2[5]) << 20);
        ep[2] = (unsigned)q10(d2[6]) | ((unsigned)q10(d2[7]) << 10) | (id2 << 20);
    } else {
        float* r = out_u + (size_t)i2 * NU;
#pragma unroll
        for (int i = 0; i < NC; ++i) atomicAdd(r + i, d2[i]);
    }
}

__global__ __launch_bounds__(BT, 4)
void bin_edges_kernel(const float* __restrict__ binary,
                      const float* __restrict__ bcw,
                      const int* __restrict__ index1,
                      const int* __restrict__ index2,
                      const float* __restrict__ u_lo,
                      float* __restrict__ out_b,       // [n_edges*4]
                      unsigned* __restrict__ cursor,   // [T], zeroed
                      unsigned* __restrict__ entries,  // [T*cap*3 u32]
                      float* __restrict__ out_u,       // overflow path only
                      int n_edges, int T, int cap, int chunk) {
    __shared__ unsigned hist[256];
    __shared__ int ic1[CACHE_N];
    __shared__ int ic2[CACHE_N];
    int tid = threadIdx.x;
    for (int t = tid; t < T; t += BT) hist[t] = 0u;
    __syncthreads();

    int e0 = blockIdx.x * chunk;
    int e1 = e0 + chunk; if (e1 > n_edges) e1 = n_edges;

    // pass 1: cache indices in LDS + local histogram (nt loads: single-use stream)
    for (int e = e0 + tid; e < e1; e += BT) {
        int i1 = __builtin_nontemporal_load(index1 + e);
        int i2 = __builtin_nontemporal_load(index2 + e);
        int l = e - e0;
        ic1[l] = i1;
        ic2[l] = i2;
        atomicAdd(&hist[(unsigned)i1 / TILE_N], 1u);
        atomicAdd(&hist[(unsigned)i2 / TILE_N], 1u);
    }
    __syncthreads();

    // reserve ranges: one global atomic per (block, nonzero bin)
    for (int t = tid; t < T; t += BT) {
        unsigned c = hist[t];
        unsigned base = 0u;
        if (c) base = atomicAdd(&cursor[t], c);
        hist[t] = base;
    }
    __syncthreads();

    float w[NC];
#pragma unroll
    for (int i = 0; i < NC; ++i) w[i] = bcw[i];

    // pass 2: 2x unrolled — two independent gather chains in flight.
    int eA = e0 + tid;
    for (; eA + BT < e1; eA += 2 * BT) {
        int eB = eA + BT;
        int lA = eA - e0, lB = eB - e0;
        int i1A = ic1[lA], i2A = ic2[lA];
        int i1B = ic1[lB], i2B = ic2[lB];

        f32x4 bvA = __builtin_nontemporal_load(((const f32x4*)binary) + eA);
        f32x4 bvB = __builtin_nontemporal_load(((const f32x4*)binary) + eB);

        const float4* p1A = (const float4*)(u_lo + (size_t)i1A * 8);
        const float4* p2A = (const float4*)(u_lo + (size_t)i2A * 8);
        const float4* p1B = (const float4*)(u_lo + (size_t)i1B * 8);
        const float4* p2B = (const float4*)(u_lo + (size_t)i2B * 8);
        float4 a0A = p1A[0], a1A = p1A[1];
        float4 c0A = p2A[0], c1A = p2A[1];
        float4 a0B = p1B[0], a1B = p1B[1];
        float4 c0B = p2B[0], c1B = p2B[1];

        edge_body(eA, i1A, i2A, bvA, a0A, a1A, c0A, c1A,
                  w, out_b, hist, entries, out_u, cap);
        edge_body(eB, i1B, i2B, bvB, a0B, a1B, c0B, c1B,
                  w, out_b, hist, entries, out_u, cap);
    }
    if (eA < e1) {
        int lA = eA - e0;
        int i1A = ic1[lA], i2A = ic2[lA];
        f32x4 bvA = __builtin_nontemporal_load(((const f32x4*)binary) + eA);
        const float4* p1A = (const float4*)(u_lo + (size_t)i1A * 8);
        const float4* p2A = (const float4*)(u_lo + (size_t)i2A * 8);
        float4 a0A = p1A[0], a1A = p1A[1];
        float4 c0A = p2A[0], c1A = p2A[1];
        edge_body(eA, i1A, i2A, bvA, a0A, a1A, c0A, c1A,
                  w, out_b, hist, entries, out_u, cap);
    }
}

// Accumulate pass: 12B entries, 4-entry groups as 3x dwordx4; 1024 threads;
// 4-way lane-replicated accumulators (rep = tid&3) to cut same-address
// ds_add_u64 serialization; replica pitch 404 staggers banks by 8.
__global__ __launch_bounds__(BTA)
void tile_acc_kernel(const unsigned* __restrict__ cursor,
                     const unsigned* __restrict__ entries,
                     float* __restrict__ out_u,
                     int n_nodes, int cap) {
    __shared__ unsigned long long acc[8 * ACC_PITCH];  // lo: reps 0-3, hi: reps 4-7
    int t = blockIdx.x;
    int tid = threadIdx.x;
    for (int i = tid; i < 8 * ACC_PITCH; i += BTA) acc[i] = 0ull;
    __syncthreads();

    unsigned cnt = cursor[t];
    if (cnt > (unsigned)cap) cnt = (unsigned)cap;
    size_t base = (size_t)t * cap;

    unsigned rep = (unsigned)(tid & 3);
    unsigned long long* accLo = acc + rep * ACC_PITCH;
    unsigned long long* accHi = acc + (4u + rep) * ACC_PITCH;

    unsigned cnt4 = cnt & ~3u;
    for (unsigned i = (unsigned)tid * 4; i < cnt4; i += BTA * 4) {
        const u32x4* p = (const u32x4*)(entries + (base + i) * 3);
        u32x4 q0 = __builtin_nontemporal_load(p + 0);
        u32x4 q1 = __builtin_nontemporal_load(p + 1);
        u32x4 q2 = __builtin_nontemporal_load(p + 2);
        unsigned d[12] = {q0.x, q0.y, q0.z, q0.w,
                          q1.x, q1.y, q1.z, q1.w,
                          q2.x, q2.y, q2.z, q2.w};
#pragma unroll
        for (int k = 0; k < 4; ++k) {
            unsigned wx = d[3*k], wy = d[3*k+1], wz = d[3*k+2];
            unsigned id = wz >> 20;
            unsigned long long lo = pk4(sx10(wx, 0), sx10(wx, 10), sx10(wx, 20), sx10(wy, 0));
            unsigned long long hi = pk4(sx10(wy, 10), sx10(wy, 20), sx10(wz, 0), sx10(wz, 10));
            atomicAdd(&accLo[id], lo);
            atomicAdd(&accHi[id], hi);
        }
    }
    for (unsigned i = cnt4 + tid; i < cnt; i += BTA) {
        const unsigned* ep = entries + (base + i) * 3;
        unsigned wx = ep[0], wy = ep[1], wz = ep[2];
        unsigned id = wz >> 20;
        unsigned long long lo = pk4(sx10(wx, 0), sx10(wx, 10), sx10(wx, 20), sx10(wy, 0));
        unsigned long long hi = pk4(sx10(wy, 10), sx10(wy, 20), sx10(wz, 0), sx10(wz, 10));
        atomicAdd(&accLo[id], lo);
        atomicAdd(&accHi[id], hi);
    }
    __syncthreads();

    const float INV = 1.0f / 512.0f;
    int nbase = t * (int)TILE_N;
    for (int l = tid; l < (int)TILE_N; l += BTA) {
        int n = nbase + l;
        if (n >= n_nodes) continue;
        // fold 4 replicas — packed mixed-radix values are additive
        unsigned long long S0 = acc[0*ACC_PITCH + l] + acc[1*ACC_PITCH + l]
                              + acc[2*ACC_PITCH + l] + acc[3*ACC_PITCH + l];
        unsigned long long S1 = acc[4*ACC_PITCH + l] + acc[5*ACC_PITCH + l]
                              + acc[6*ACC_PITCH + l] + acc[7*ACC_PITCH + l];
        float col[8];
        unsigned long long S = S0;
#pragma unroll
        for (int f = 0; f < 4; ++f) {
            short s = (short)(S & 0xFFFFull);
            col[f] = (float)s * INV;
            S = (S - (unsigned long long)(long long)s) >> 16;
        }
        S = S1;
#pragma unroll
        for (int f = 0; f < 4; ++f) {
            short s = (short)(S & 0xFFFFull);
            col[4 + f] = (float)s * INV;
            S = (S - (unsigned long long)(long long)s) >> 16;
        }
        float4* row = (float4*)(out_u + (size_t)n * NU);
        float4 r0 = row[0], r1 = row[1];
        r0.x += col[0]; r0.y += col[1]; r0.z += col[2]; r0.w += col[3];
        r1.x += col[4]; r1.y += col[5]; r1.z += col[6]; r1.w += col[7];
        row[0] = r0; row[1] = r1;
    }
}

// Fallback (R1): device-scope atomics, needs only u_lo in ws.
__global__ void edge_enhance_kernel(const float* __restrict__ binary,
                                    const float* __restrict__ bcw,
                                    const int* __restrict__ index1,
                                    const int* __restrict__ index2,
                                    const float* __restrict__ u_lo,
                                    float* __restrict__ out_u,
                                    float* __restrict__ out_b,
                                    int n_edges) {
    int e = blockIdx.x * blockDim.x + threadIdx.x;
    if (e >= n_edges) return;

    int i1 = index1[e];
    int i2 = index2[e];
    float4 bv = ((const float4*)binary)[e];
    float b[4] = {bv.x, bv.y, bv.z, bv.w};

    const float4* p1 = (const float4*)(u_lo + (size_t)i1 * 8);
    float4 a0 = p1[0], a1 = p1[1];
    const float4* p2 = (const float4*)(u_lo + (size_t)i2 * 8);
    float4 c0 = p2[0], c1 = p2[1];
    float u1[8] = {a0.x,a0.y,a0.z,a0.w,a1.x,a1.y,a1.z,a1.w};
    float u2[8] = {c0.x,c0.y,c0.z,c0.w,c1.x,c1.y,c1.z,c1.w};

    float d1[8], d2[8], dbp[4] = {0.f,0.f,0.f,0.f};
#pragma unroll
    for (int i = 0; i < NC; ++i) {
        float w = bcw[i];
        float a = -u1[i], bb = b[i & 3], c = u2[i];
        float m = fmaxf(a, fmaxf(bb, c));
        float e0 = __expf(a - m);
        float e1 = __expf(bb - m);
        float e2 = __expf(c - m);
        float inv = 1.0f / (e0 + e1 + e2);
        d1[i] = -w * e0 * inv;
        d2[i] =  w * e2 * inv;
        dbp[i & 3] += w * e1 * inv;
    }
    float* r1 = out_u + (size_t)i1 * NU;
#pragma unroll
    for (int i = 0; i < NC; ++i) atomicAdd(r1 + i, d1[i]);
    float* r2 = out_u + (size_t)i2 * NU;
#pragma unroll
    for (int i = 0; i < NC; ++i) atomicAdd(r2 + i, d2[i]);

    float4 ob;
    ob.x = b[0] + dbp[0];
    ob.y = b[1] + dbp[1];
    ob.z = b[2] + dbp[2];
    ob.w = b[3] + dbp[3];
    ((float4*)out_b)[e] = ob;
}

extern "C" void kernel_launch(void* const* d_in, const int* in_sizes, int n_in,
                              void* d_out, int out_size, void* d_ws, size_t ws_size,
                              hipStream_t stream) {
    const float* unary  = (const float*)d_in[0];
    const float* binary = (const float*)d_in[1];
    const float* ucw    = (const float*)d_in[2];
    const float* bcw    = (const float*)d_in[3];
    const int*   index1 = (const int*)d_in[4];
    const int*   index2 = (const int*)d_in[5];

    int n_nodes = in_sizes[0] / NU;
    int n_edges = in_sizes[4];

    float* out_u = (float*)d_out;
    float* out_b = out_u + (size_t)n_nodes * NU;

    int T = (int)(((unsigned)n_nodes + TILE_N - 1) / TILE_N);   // 250
    size_t mean = (2ull * (size_t)n_edges) / (size_t)T;
    int cap = (int)(mean + mean / 8 + 512);
    cap = (cap + 3) & ~3;

    int chunk = (n_edges + NB - 1) / NB;                        // 3125

    // ws layout: u_lo [n_nodes*8 f32] | entries [T*cap*3 u32] | cursor [T u32]
    size_t u_lo_bytes  = (size_t)n_nodes * 8 * sizeof(float);
    size_t ent_off     = (u_lo_bytes + 63) & ~(size_t)63;       // 48B-group align
    size_t ent_bytes   = (size_t)T * cap * 12;
    size_t cur_off     = ent_off + ent_bytes;
    size_t cur_bytes   = (size_t)T * 4;
    size_t need        = cur_off + cur_bytes;

    float* u_lo = (float*)d_ws;
    unsigned* entries = (unsigned*)((char*)d_ws + ent_off);
    unsigned* cursor = (unsigned*)((char*)d_ws + cur_off);

    bool fast = (ws_size >= need && T <= 256 && chunk <= CACHE_N);

    int tb = 256;
    unary_enhance_kernel<<<(n_nodes + tb - 1) / tb, tb, 0, stream>>>(
        unary, ucw, out_u, u_lo, fast ? cursor : (unsigned*)nullptr, n_nodes, T);

    if (fast) {
        bin_edges_kernel<<<NB, BT, 0, stream>>>(
            binary, bcw, index1, index2, u_lo, out_b,
            cursor, entries, out_u, n_edges, T, cap, chunk);
        tile_acc_kernel<<<T, BTA, 0, stream>>>(
            cursor, entries, out_u, n_nodes, cap);
    } else {
        edge_enhance_kernel<<<(n_edges + tb - 1) / tb, tb, 0, stream>>>(
            binary, bcw, index1, index2, u_lo, out_u, out_b, n_edges);
    }
}

// Round 14
// 183.026 us; speedup vs baseline: 1.0210x; 1.0210x over previous
//
#include <hip/hip_runtime.h>
#include <math.h>

// RelationalKENN R20: R18 body + pass-2 ILP 2x -> 4x (MLP probe on bin).
//
// Ledger:
//  R10 global packed-u64 atomics: REFUTED (~32B HBM write each, 287us).
//  R11/R16 NB=1024: REFUTED TWICE — bin is L2-capacity-bound. NB=512 final.
//  R12 cooperative fusion: REFUTED (252us).
//  R13b nt-everything: nt loads fix u_lo thrash (FETCH 84->33MB); nt entries
//      store breaks write-combining (reverted).
//  R14 nt loads + nt out_b: WIN (190.3).
//  R15 pass-2 atomic removal: NEUTRAL — atomics exonerated.
//  R17 TILE_N=200: WASH — bin/acc coupled via T; T=250 best.
//  R18 12B entries + 1024-thr acc: WIN (185.4). BEST.
//  R19 4-way replicated acc: NULL (186.9) — acc is at its ~43us LDS-atomic
//      throughput floor, collision-insensitive. Reverted.
//  R20: bin 88us vs ~42us floor; atomics/occupancy/T all exonerated ->
//      surviving hypothesis: gather-chain MLP starvation (only 2 chains/
//      thread). Unroll pass 2 to 4 edges: 4 nt binary + 8 u_lo gathers in
//      flight before first consume. Predict bin ->78-83, total ->178-182.
//      Falsifier: bin flat >=86 => structure converged; declare next round.

#define NU 16
#define NC 8
#define TILE_N 400u
#define NB 512        // bin-pass blocks
#define BT 512        // bin-pass block size
#define CACHE_N 3200  // max edges cached per bin block (chunk = 3125)
#define ACC_ST 400
#define BTA 1024      // tile_acc block size

typedef float    f32x4 __attribute__((ext_vector_type(4)));
typedef unsigned u32x4 __attribute__((ext_vector_type(4)));

__device__ __forceinline__ int q10(float x) {
    int q = __float2int_rn(x * 512.0f);
    q = q < -511 ? -511 : (q > 511 ? 511 : q);
    return q & 0x3FF;
}
__device__ __forceinline__ int sx10(unsigned w, int sh) {
    return ((int)(w << (22 - sh))) >> 22;
}
__device__ __forceinline__ unsigned long long pk4(int a0, int a1, int a2, int a3) {
    return (unsigned long long)(long long)a0 +
           ((unsigned long long)(long long)a1 << 16) +
           ((unsigned long long)(long long)a2 << 32) +
           ((unsigned long long)(unsigned short)a3 << 48);
}

__global__ void unary_enhance_kernel(const float* __restrict__ unary,
                                     const float* __restrict__ ucw,
                                     float* __restrict__ out_u,   // [n_nodes*16]
                                     float* __restrict__ u_lo,    // [n_nodes*8]
                                     unsigned* __restrict__ cursor, // [T] or null
                                     int n_nodes, int T) {
    int n = blockIdx.x * blockDim.x + threadIdx.x;
    if (cursor && n < T) cursor[n] = 0u;
    if (n >= n_nodes) return;

    float x[NU];
    const float4* src = (const float4*)(unary + (size_t)n * NU);
#pragma unroll
    for (int j = 0; j < 4; ++j) {
        float4 v = src[j];
        x[4*j+0] = v.x; x[4*j+1] = v.y; x[4*j+2] = v.z; x[4*j+3] = v.w;
    }
    float dlt[NU];
#pragma unroll
    for (int j = 0; j < NU; ++j) dlt[j] = 0.0f;
#pragma unroll
    for (int i = 0; i < NC; ++i) {
        float w = ucw[i];
        float a = -x[i], b = x[i+1], c = x[i+2];
        float m = fmaxf(a, fmaxf(b, c));
        float e0 = __expf(a - m);
        float e1 = __expf(b - m);
        float e2 = __expf(c - m);
        float inv = 1.0f / (e0 + e1 + e2);
        dlt[i]   -= w * e0 * inv;
        dlt[i+1] += w * e1 * inv;
        dlt[i+2] += w * e2 * inv;
    }
    float u[NU];
#pragma unroll
    for (int j = 0; j < NU; ++j) u[j] = x[j] + dlt[j];

    float4* dst = (float4*)(out_u + (size_t)n * NU);
#pragma unroll
    for (int j = 0; j < 4; ++j) {
        float4 v; v.x = u[4*j+0]; v.y = u[4*j+1]; v.z = u[4*j+2]; v.w = u[4*j+3];
        dst[j] = v;
    }
    // u_lo: NORMAL store — we WANT it resident in L2 for bin's gathers.
    float4* lo = (float4*)(u_lo + (size_t)n * 8);
    float4 l0; l0.x = u[0]; l0.y = u[1]; l0.z = u[2]; l0.w = u[3];
    float4 l1; l1.x = u[4]; l1.y = u[5]; l1.z = u[6]; l1.w = u[7];
    lo[0] = l0; lo[1] = l1;
}

// Softmax + out_b + 2 scatter entries (12B each) for one edge.
__device__ __forceinline__ void edge_body(int e, int i1, int i2, f32x4 bv,
                                          float4 a0, float4 a1, float4 c0, float4 c1,
                                          const float* w,
                                          float* __restrict__ out_b,
                                          unsigned* hist,
                                          unsigned* __restrict__ entries,
                                          float* __restrict__ out_u,
                                          int cap) {
    float b[4] = {bv.x, bv.y, bv.z, bv.w};
    float u1[8] = {a0.x,a0.y,a0.z,a0.w,a1.x,a1.y,a1.z,a1.w};
    float u2[8] = {c0.x,c0.y,c0.z,c0.w,c1.x,c1.y,c1.z,c1.w};

    float d1[8], d2[8], dbp[4] = {0.f,0.f,0.f,0.f};
#pragma unroll
    for (int i = 0; i < NC; ++i) {
        float a = -u1[i], bb = b[i & 3], c = u2[i];
        float m = fmaxf(a, fmaxf(bb, c));
        float e0x = __expf(a - m);
        float e1x = __expf(bb - m);
        float e2x = __expf(c - m);
        float inv = 1.0f / (e0x + e1x + e2x);
        d1[i] = -w[i] * e0x * inv;
        d2[i] =  w[i] * e2x * inv;
        dbp[i & 3] += w[i] * e1x * inv;
    }
    f32x4 ob;
    ob.x = b[0] + dbp[0];
    ob.y = b[1] + dbp[1];
    ob.z = b[2] + dbp[2];
    ob.w = b[3] + dbp[3];
    // coalesced 1KB/wave stream: nt write-combines fine, no L2 pollution
    __builtin_nontemporal_store(ob, ((f32x4*)out_b) + e);

    unsigned t1 = (unsigned)i1 / TILE_N;
    unsigned id1 = (unsigned)i1 - t1 * TILE_N;
    unsigned slot1 = atomicAdd(&hist[t1], 1u);
    if (slot1 < (unsigned)cap) {
        unsigned* ep = entries + ((size_t)t1 * cap + slot1) * 3;
        ep[0] = (unsigned)q10(d1[0]) | ((unsigned)q10(d1[1]) << 10) | ((unsigned)q10(d1[2]) << 20);
        ep[1] = (unsigned)q10(d1[3]) | ((unsigned)q10(d1[4]) << 10) | ((unsigned)q10(d1[5]) << 20);
        ep[2] = (unsigned)q10(d1[6]) | ((unsigned)q10(d1[7]) << 10) | (id1 << 20);
    } else {
        float* r = out_u + (size_t)i1 * NU;
#pragma unroll
        for (int i = 0; i < NC; ++i) atomicAdd(r + i, d1[i]);
    }

    unsigned t2 = (unsigned)i2 / TILE_N;
    unsigned id2 = (unsigned)i2 - t2 * TILE_N;
    unsigned slot2 = atomicAdd(&hist[t2], 1u);
    if (slot2 < (unsigned)cap) {
        unsigned* ep = entries + ((size_t)t2 * cap + slot2) * 3;
        ep[0] = (unsigned)q10(d2[0]) | ((unsigned)q10(d2[1]) << 10) | ((unsigned)q10(d2[2]) << 20);
        ep[1] = (unsigned)q10(d2[3]) | ((unsigned)q10(d2[4]) << 10) | ((unsigned)q10(d2[5]) << 20);
        ep[2] = (unsigned)q10(d2[6]) | ((unsigned)q10(d2[7]) << 10) | (id2 << 20);
    } else {
        float* r = out_u + (size_t)i2 * NU;
#pragma unroll
        for (int i = 0; i < NC; ++i) atomicAdd(r + i, d2[i]);
    }
}

__global__ __launch_bounds__(BT, 4)
void bin_edges_kernel(const float* __restrict__ binary,
                      const float* __restrict__ bcw,
                      const int* __restrict__ index1,
                      const int* __restrict__ index2,
                      const float* __restrict__ u_lo,
                      float* __restrict__ out_b,       // [n_edges*4]
                      unsigned* __restrict__ cursor,   // [T], zeroed
                      unsigned* __restrict__ entries,  // [T*cap*3 u32]
                      float* __restrict__ out_u,       // overflow path only
                      int n_edges, int T, int cap, int chunk) {
    __shared__ unsigned hist[256];
    __shared__ int ic1[CACHE_N];
    __shared__ int ic2[CACHE_N];
    int tid = threadIdx.x;
    for (int t = tid; t < T; t += BT) hist[t] = 0u;
    __syncthreads();

    int e0 = blockIdx.x * chunk;
    int e1 = e0 + chunk; if (e1 > n_edges) e1 = n_edges;

    // pass 1: cache indices in LDS + local histogram (nt loads: single-use stream)
    for (int e = e0 + tid; e < e1; e += BT) {
        int i1 = __builtin_nontemporal_load(index1 + e);
        int i2 = __builtin_nontemporal_load(index2 + e);
        int l = e - e0;
        ic1[l] = i1;
        ic2[l] = i2;
        atomicAdd(&hist[(unsigned)i1 / TILE_N], 1u);
        atomicAdd(&hist[(unsigned)i2 / TILE_N], 1u);
    }
    __syncthreads();

    // reserve ranges: one global atomic per (block, nonzero bin)
    for (int t = tid; t < T; t += BT) {
        unsigned c = hist[t];
        unsigned base = 0u;
        if (c) base = atomicAdd(&cursor[t], c);
        hist[t] = base;
    }
    __syncthreads();

    float w[NC];
#pragma unroll
    for (int i = 0; i < NC; ++i) w[i] = bcw[i];

    // pass 2: 4x unrolled — four independent gather chains in flight.
    int eA = e0 + tid;
    for (; eA + 3 * BT < e1; eA += 4 * BT) {
        int eB = eA + BT, eC = eA + 2 * BT, eD = eA + 3 * BT;
        int lA = eA - e0, lB = eB - e0, lC = eC - e0, lD = eD - e0;
        int i1A = ic1[lA], i2A = ic2[lA];
        int i1B = ic1[lB], i2B = ic2[lB];
        int i1C = ic1[lC], i2C = ic2[lC];
        int i1D = ic1[lD], i2D = ic2[lD];

        f32x4 bvA = __builtin_nontemporal_load(((const f32x4*)binary) + eA);
        f32x4 bvB = __builtin_nontemporal_load(((const f32x4*)binary) + eB);
        f32x4 bvC = __builtin_nontemporal_load(((const f32x4*)binary) + eC);
        f32x4 bvD = __builtin_nontemporal_load(((const f32x4*)binary) + eD);

        const float4* p1A = (const float4*)(u_lo + (size_t)i1A * 8);
        const float4* p2A = (const float4*)(u_lo + (size_t)i2A * 8);
        const float4* p1B = (const float4*)(u_lo + (size_t)i1B * 8);
        const float4* p2B = (const float4*)(u_lo + (size_t)i2B * 8);
        const float4* p1C = (const float4*)(u_lo + (size_t)i1C * 8);
        const float4* p2C = (const float4*)(u_lo + (size_t)i2C * 8);
        const float4* p1D = (const float4*)(u_lo + (size_t)i1D * 8);
        const float4* p2D = (const float4*)(u_lo + (size_t)i2D * 8);
        float4 a0A = p1A[0], a1A = p1A[1], c0A = p2A[0], c1A = p2A[1];
        float4 a0B = p1B[0], a1B = p1B[1], c0B = p2B[0], c1B = p2B[1];
        float4 a0C = p1C[0], a1C = p1C[1], c0C = p2C[0], c1C = p2C[1];
        float4 a0D = p1D[0], a1D = p1D[1], c0D = p2D[0], c1D = p2D[1];

        edge_body(eA, i1A, i2A, bvA, a0A, a1A, c0A, c1A,
                  w, out_b, hist, entries, out_u, cap);
        edge_body(eB, i1B, i2B, bvB, a0B, a1B, c0B, c1B,
                  w, out_b, hist, entries, out_u, cap);
        edge_body(eC, i1C, i2C, bvC, a0C, a1C, c0C, c1C,
                  w, out_b, hist, entries, out_u, cap);
        edge_body(eD, i1D, i2D, bvD, a0D, a1D, c0D, c1D,
                  w, out_b, hist, entries, out_u, cap);
    }
    for (; eA < e1; eA += BT) {
        int lA = eA - e0;
        int i1A = ic1[lA], i2A = ic2[lA];
        f32x4 bvA = __builtin_nontemporal_load(((const f32x4*)binary) + eA);
        const float4* p1A = (const float4*)(u_lo + (size_t)i1A * 8);
        const float4* p2A = (const float4*)(u_lo + (size_t)i2A * 8);
        float4 a0A = p1A[0], a1A = p1A[1];
        float4 c0A = p2A[0], c1A = p2A[1];
        edge_body(eA, i1A, i2A, bvA, a0A, a1A, c0A, c1A,
                  w, out_b, hist, entries, out_u, cap);
    }
}

// Accumulate pass (R18): 12B entries, 4-entry groups as 3x dwordx4; 1024 thr.
__global__ __launch_bounds__(BTA)
void tile_acc_kernel(const unsigned* __restrict__ cursor,
                     const unsigned* __restrict__ entries,
                     float* __restrict__ out_u,
                     int n_nodes, int cap) {
    __shared__ unsigned long long acc[2 * ACC_ST];
    int t = blockIdx.x;
    int tid = threadIdx.x;
    for (int i = tid; i < 2 * ACC_ST; i += BTA) acc[i] = 0ull;
    __syncthreads();

    unsigned cnt = cursor[t];
    if (cnt > (unsigned)cap) cnt = (unsigned)cap;
    size_t base = (size_t)t * cap;

    unsigned cnt4 = cnt & ~3u;
    for (unsigned i = (unsigned)tid * 4; i < cnt4; i += BTA * 4) {
        const u32x4* p = (const u32x4*)(entries + (base + i) * 3);
        u32x4 q0 = __builtin_nontemporal_load(p + 0);
        u32x4 q1 = __builtin_nontemporal_load(p + 1);
        u32x4 q2 = __builtin_nontemporal_load(p + 2);
        unsigned d[12] = {q0.x, q0.y, q0.z, q0.w,
                          q1.x, q1.y, q1.z, q1.w,
                          q2.x, q2.y, q2.z, q2.w};
#pragma unroll
        for (int k = 0; k < 4; ++k) {
            unsigned wx = d[3*k], wy = d[3*k+1], wz = d[3*k+2];
            unsigned id = wz >> 20;
            unsigned long long lo = pk4(sx10(wx, 0), sx10(wx, 10), sx10(wx, 20), sx10(wy, 0));
            unsigned long long hi = pk4(sx10(wy, 10), sx10(wy, 20), sx10(wz, 0), sx10(wz, 10));
            atomicAdd(&acc[id], lo);
            atomicAdd(&acc[ACC_ST + id], hi);
        }
    }
    for (unsigned i = cnt4 + tid; i < cnt; i += BTA) {
        const unsigned* ep = entries + (base + i) * 3;
        unsigned wx = ep[0], wy = ep[1], wz = ep[2];
        unsigned id = wz >> 20;
        unsigned long long lo = pk4(sx10(wx, 0), sx10(wx, 10), sx10(wx, 20), sx10(wy, 0));
        unsigned long long hi = pk4(sx10(wy, 10), sx10(wy, 20), sx10(wz, 0), sx10(wz, 10));
        atomicAdd(&acc[id], lo);
        atomicAdd(&acc[ACC_ST + id], hi);
    }
    __syncthreads();

    const float INV = 1.0f / 512.0f;
    int nbase = t * (int)TILE_N;
    for (int l = tid; l < (int)TILE_N; l += BTA) {
        int n = nbase + l;
        if (n >= n_nodes) continue;
        float col[8];
#pragma unroll
        for (int wd = 0; wd < 2; ++wd) {
            unsigned long long S = acc[wd*ACC_ST + l];
#pragma unroll
            for (int f = 0; f < 4; ++f) {
                short s = (short)(S & 0xFFFFull);
                col[wd*4 + f] = (float)s * INV;
                S = (S - (unsigned long long)(long long)s) >> 16;
            }
        }
        float4* row = (float4*)(out_u + (size_t)n * NU);
        float4 r0 = row[0], r1 = row[1];
        r0.x += col[0]; r0.y += col[1]; r0.z += col[2]; r0.w += col[3];
        r1.x += col[4]; r1.y += col[5]; r1.z += col[6]; r1.w += col[7];
        row[0] = r0; row[1] = r1;
    }
}

// Fallback (R1): device-scope atomics, needs only u_lo in ws.
__global__ void edge_enhance_kernel(const float* __restrict__ binary,
                                    const float* __restrict__ bcw,
                                    const int* __restrict__ index1,
                                    const int* __restrict__ index2,
                                    const float* __restrict__ u_lo,
                                    float* __restrict__ out_u,
                                    float* __restrict__ out_b,
                                    int n_edges) {
    int e = blockIdx.x * blockDim.x + threadIdx.x;
    if (e >= n_edges) return;

    int i1 = index1[e];
    int i2 = index2[e];
    float4 bv = ((const float4*)binary)[e];
    float b[4] = {bv.x, bv.y, bv.z, bv.w};

    const float4* p1 = (const float4*)(u_lo + (size_t)i1 * 8);
    float4 a0 = p1[0], a1 = p1[1];
    const float4* p2 = (const float4*)(u_lo + (size_t)i2 * 8);
    float4 c0 = p2[0], c1 = p2[1];
    float u1[8] = {a0.x,a0.y,a0.z,a0.w,a1.x,a1.y,a1.z,a1.w};
    float u2[8] = {c0.x,c0.y,c0.z,c0.w,c1.x,c1.y,c1.z,c1.w};

    float d1[8], d2[8], dbp[4] = {0.f,0.f,0.f,0.f};
#pragma unroll
    for (int i = 0; i < NC; ++i) {
        float w = bcw[i];
        float a = -u1[i], bb = b[i & 3], c = u2[i];
        float m = fmaxf(a, fmaxf(bb, c));
        float e0 = __expf(a - m);
        float e1 = __expf(bb - m);
        float e2 = __expf(c - m);
        float inv = 1.0f / (e0 + e1 + e2);
        d1[i] = -w * e0 * inv;
        d2[i] =  w * e2 * inv;
        dbp[i & 3] += w * e1 * inv;
    }
    float* r1 = out_u + (size_t)i1 * NU;
#pragma unroll
    for (int i = 0; i < NC; ++i) atomicAdd(r1 + i, d1[i]);
    float* r2 = out_u + (size_t)i2 * NU;
#pragma unroll
    for (int i = 0; i < NC; ++i) atomicAdd(r2 + i, d2[i]);

    float4 ob;
    ob.x = b[0] + dbp[0];
    ob.y = b[1] + dbp[1];
    ob.z = b[2] + dbp[2];
    ob.w = b[3] + dbp[3];
    ((float4*)out_b)[e] = ob;
}

extern "C" void kernel_launch(void* const* d_in, const int* in_sizes, int n_in,
                              void* d_out, int out_size, void* d_ws, size_t ws_size,
                              hipStream_t stream) {
    const float* unary  = (const float*)d_in[0];
    const float* binary = (const float*)d_in[1];
    const float* ucw    = (const float*)d_in[2];
    const float* bcw    = (const float*)d_in[3];
    const int*   index1 = (const int*)d_in[4];
    const int*   index2 = (const int*)d_in[5];

    int n_nodes = in_sizes[0] / NU;
    int n_edges = in_sizes[4];

    float* out_u = (float*)d_out;
    float* out_b = out_u + (size_t)n_nodes * NU;

    int T = (int)(((unsigned)n_nodes + TILE_N - 1) / TILE_N);   // 250
    size_t mean = (2ull * (size_t)n_edges) / (size_t)T;
    int cap = (int)(mean + mean / 8 + 512);
    cap = (cap + 3) & ~3;

    int chunk = (n_edges + NB - 1) / NB;                        // 3125

    // ws layout: u_lo [n_nodes*8 f32] | entries [T*cap*3 u32] | cursor [T u32]
    size_t u_lo_bytes  = (size_t)n_nodes * 8 * sizeof(float);
    size_t ent_off     = (u_lo_bytes + 63) & ~(size_t)63;       // 48B-group align
    size_t ent_bytes   = (size_t)T * cap * 12;
    size_t cur_off     = ent_off + ent_bytes;
    size_t cur_bytes   = (size_t)T * 4;
    size_t need        = cur_off + cur_bytes;

    float* u_lo = (float*)d_ws;
    unsigned* entries = (unsigned*)((char*)d_ws + ent_off);
    unsigned* cursor = (unsigned*)((char*)d_ws + cur_off);

    bool fast = (ws_size >= need && T <= 256 && chunk <= CACHE_N);

    int tb = 256;
    unary_enhance_kernel<<<(n_nodes + tb - 1) / tb, tb, 0, stream>>>(
        unary, ucw, out_u, u_lo, fast ? cursor : (unsigned*)nullptr, n_nodes, T);

    if (fast) {
        bin_edges_kernel<<<NB, BT, 0, stream>>>(
            binary, bcw, index1, index2, u_lo, out_b,
            cursor, entries, out_u, n_edges, T, cap, chunk);
        tile_acc_kernel<<<T, BTA, 0, stream>>>(
            cursor, entries, out_u, n_nodes, cap);
    } else {
        edge_enhance_kernel<<<(n_edges + tb - 1) / tb, tb, 0, stream>>>(
            binary, bcw, index1, index2, u_lo, out_u, out_b, n_edges);
    }
}